// Round 1
// baseline (555.869 us; speedup 1.0000x reference)
//
#include <hip/hip_runtime.h>
#include <cstdint>
#include <cstddef>

#define B_ 8
#define T_ 2048
#define E_ 1024
#define D_ 64

// ---------------- QKV projection ----------------
// x: [B*T, E] f32 ; Wq/Wk/Wv: [E, D] f32 ; Q/K/V out: [B*T, D] f32
// Block: 256 threads = 4 row-groups x 64 d-lanes. 16 rows per block staged in LDS.
#define PROJ_ROWS 16
__global__ __launch_bounds__(256) void qkv_proj_kernel(
    const float* __restrict__ x, const float* __restrict__ Wq,
    const float* __restrict__ Wk, const float* __restrict__ Wv,
    float* __restrict__ Qo, float* __restrict__ Ko, float* __restrict__ Vo)
{
    __shared__ float xs[PROJ_ROWS][E_];   // 64 KB
    const int tid = threadIdx.x;
    const long rowBase = (long)blockIdx.x * PROJ_ROWS;

    // cooperative float4 load of 16 rows of x
    const float4* src = (const float4*)(x + rowBase * E_);
    float4* dst = (float4*)&xs[0][0];
    #pragma unroll
    for (int i = 0; i < (PROJ_ROWS * E_ / 4) / 256; ++i)
        dst[tid + 256 * i] = src[tid + 256 * i];
    __syncthreads();

    const int qg = tid >> 6;   // row-group 0..3
    const int d  = tid & 63;

    float aq[4] = {0.f,0.f,0.f,0.f};
    float ak[4] = {0.f,0.f,0.f,0.f};
    float av[4] = {0.f,0.f,0.f,0.f};

    for (int e = 0; e < E_; ++e) {
        const float wq = Wq[e * D_ + d];
        const float wk = Wk[e * D_ + d];
        const float wv = Wv[e * D_ + d];
        #pragma unroll
        for (int k = 0; k < 4; ++k) {
            const float xv = xs[qg + 4 * k][e];   // LDS broadcast within wave
            aq[k] = fmaf(xv, wq, aq[k]);
            ak[k] = fmaf(xv, wk, ak[k]);
            av[k] = fmaf(xv, wv, av[k]);
        }
    }
    #pragma unroll
    for (int k = 0; k < 4; ++k) {
        const long row = rowBase + qg + 4 * k;
        Qo[row * D_ + d] = aq[k];
        Ko[row * D_ + d] = ak[k];
        Vo[row * D_ + d] = av[k];
    }
}

// ---------------- causal attention ----------------
// 4 query rows per block; full score row in LDS; two-pass softmax; coalesced PV.
#define QR 4
__global__ __launch_bounds__(256) void attn_kernel(
    const float* __restrict__ Q, const float* __restrict__ K,
    const float* __restrict__ V, float* __restrict__ out)
{
    __shared__ float sc[QR][T_];      // 32 KB score rows (then p rows)
    __shared__ float qs[QR][D_];      // 1 KB
    __shared__ float red[4][QR][D_];  // 4 KB PV partials
    __shared__ float rr[QR][256];     // 4 KB reductions

    const int tid = threadIdx.x;
    const int blk = blockIdx.x;
    const int b   = blk >> 9;             // T_/QR = 512 blocks per batch
    const int tq  = (blk & 511) * QR;     // base query row

    const float* Qb = Q + ((size_t)b * T_ + tq) * D_;
    const float* Kb = K + (size_t)b * T_ * D_;
    const float* Vb = V + (size_t)b * T_ * D_;

    // load + pre-scale q rows (1/sqrt(64) = 0.125)
    for (int i = tid; i < QR * D_; i += 256)
        qs[i >> 6][i & 63] = Qb[i] * 0.125f;
    __syncthreads();

    const int nk = tq + QR;   // keys 0..nk-1 touched; per-row causal mask below

    // ---- scores + per-thread max ----
    float lm0 = -1e30f, lm1 = -1e30f, lm2 = -1e30f, lm3 = -1e30f;
    for (int s = tid; s < nk; s += 256) {
        const float* kp = Kb + (size_t)s * D_;
        float a0 = 0.f, a1 = 0.f, a2 = 0.f, a3 = 0.f;
        #pragma unroll 16
        for (int d2 = 0; d2 < D_; ++d2) {
            const float kd = kp[d2];
            a0 = fmaf(qs[0][d2], kd, a0);
            a1 = fmaf(qs[1][d2], kd, a1);
            a2 = fmaf(qs[2][d2], kd, a2);
            a3 = fmaf(qs[3][d2], kd, a3);
        }
        if (s > tq + 0) a0 = -1e30f;
        if (s > tq + 1) a1 = -1e30f;
        if (s > tq + 2) a2 = -1e30f;
        if (s > tq + 3) a3 = -1e30f;
        sc[0][s] = a0; sc[1][s] = a1; sc[2][s] = a2; sc[3][s] = a3;
        lm0 = fmaxf(lm0, a0); lm1 = fmaxf(lm1, a1);
        lm2 = fmaxf(lm2, a2); lm3 = fmaxf(lm3, a3);
    }

    // ---- block max-reduce ----
    rr[0][tid] = lm0; rr[1][tid] = lm1; rr[2][tid] = lm2; rr[3][tid] = lm3;
    __syncthreads();
    for (int off = 128; off > 0; off >>= 1) {
        if (tid < off) {
            #pragma unroll
            for (int r = 0; r < QR; ++r)
                rr[r][tid] = fmaxf(rr[r][tid], rr[r][tid + off]);
        }
        __syncthreads();
    }
    const float m0 = rr[0][0], m1 = rr[1][0], m2 = rr[2][0], m3 = rr[3][0];

    // ---- exp + per-thread sum ----
    float ls0 = 0.f, ls1 = 0.f, ls2 = 0.f, ls3 = 0.f;
    for (int s = tid; s < nk; s += 256) {
        const float p0 = __expf(sc[0][s] - m0);
        const float p1 = __expf(sc[1][s] - m1);
        const float p2 = __expf(sc[2][s] - m2);
        const float p3 = __expf(sc[3][s] - m3);
        sc[0][s] = p0; sc[1][s] = p1; sc[2][s] = p2; sc[3][s] = p3;
        ls0 += p0; ls1 += p1; ls2 += p2; ls3 += p3;
    }
    __syncthreads();   // everyone done reading rr[r][0] (m) before overwrite

    // ---- block sum-reduce ----
    rr[0][tid] = ls0; rr[1][tid] = ls1; rr[2][tid] = ls2; rr[3][tid] = ls3;
    __syncthreads();
    for (int off = 128; off > 0; off >>= 1) {
        if (tid < off) {
            #pragma unroll
            for (int r = 0; r < QR; ++r)
                rr[r][tid] += rr[r][tid + off];
        }
        __syncthreads();
    }

    // ---- PV: thread = (phase c, dim d); coalesced V reads ----
    const int c = tid >> 6;
    const int d = tid & 63;
    float o0 = 0.f, o1 = 0.f, o2 = 0.f, o3 = 0.f;
    for (int s = c; s < nk; s += 4) {
        const float vv = Vb[(size_t)s * D_ + d];
        const float p0 = sc[0][s], p1 = sc[1][s], p2 = sc[2][s], p3 = sc[3][s];
        o0 = fmaf(p0, vv, o0);
        o1 = fmaf(p1, vv, o1);
        o2 = fmaf(p2, vv, o2);
        o3 = fmaf(p3, vv, o3);
    }
    red[c][0][d] = o0; red[c][1][d] = o1; red[c][2][d] = o2; red[c][3][d] = o3;
    __syncthreads();

    const int r  = tid >> 6;
    const int dd = tid & 63;
    const float osum = red[0][r][dd] + red[1][r][dd] + red[2][r][dd] + red[3][r][dd];
    const float denom = rr[r][0];
    out[((size_t)b * T_ + tq + r) * D_ + dd] = osum / denom;
}

extern "C" void kernel_launch(void* const* d_in, const int* in_sizes, int n_in,
                              void* d_out, int out_size, void* d_ws, size_t ws_size,
                              hipStream_t stream) {
    const float* x  = (const float*)d_in[0];
    const float* Wq = (const float*)d_in[1];
    const float* Wk = (const float*)d_in[2];
    const float* Wv = (const float*)d_in[3];
    float* out = (float*)d_out;

    float* Q = (float*)d_ws;                       // [B*T, D]
    float* K = Q + (size_t)B_ * T_ * D_;           // [B*T, D]
    float* V = K + (size_t)B_ * T_ * D_;           // [B*T, D]

    qkv_proj_kernel<<<(B_ * T_) / PROJ_ROWS, 256, 0, stream>>>(x, Wq, Wk, Wv, Q, K, V);
    attn_kernel<<<(B_ * T_) / QR, 256, 0, stream>>>(Q, K, V, out);
}

// Round 2
// 163.232 us; speedup vs baseline: 3.4054x; 3.4054x over previous
//
#include <hip/hip_runtime.h>
#include <hip/hip_bf16.h>
#include <cstdint>
#include <cstddef>

#define B_ 8
#define T_ 2048
#define E_ 1024
#define D_ 64

typedef __attribute__((ext_vector_type(8))) short bf16x8;
typedef __attribute__((ext_vector_type(4))) float f32x4;

__device__ __forceinline__ short f2bf(float f){
    __hip_bfloat16 h = __float2bfloat16(f);
    return *reinterpret_cast<short*>(&h);
}

__device__ __forceinline__ bf16x8 cvt8(const float4& a0, const float4& a1){
    bf16x8 r;
    r[0]=f2bf(a0.x); r[1]=f2bf(a0.y); r[2]=f2bf(a0.z); r[3]=f2bf(a0.w);
    r[4]=f2bf(a1.x); r[5]=f2bf(a1.y); r[6]=f2bf(a1.z); r[7]=f2bf(a1.w);
    return r;
}

// ---------- prologue: Wt[n][k] = W*[k][n] as bf16, n in [0,192), k in [0,1024) ----------
__global__ __launch_bounds__(256) void wconv_kernel(
    const float* __restrict__ Wq, const float* __restrict__ Wk,
    const float* __restrict__ Wv, __hip_bfloat16* __restrict__ Wt)
{
    __shared__ float tile[64][65];
    const int mb = blockIdx.x >> 4;    // 0..2 which matrix
    const int kb = blockIdx.x & 15;    // k block 0..15
    const float* W = (mb==0) ? Wq : (mb==1) ? Wk : Wv;
    const int c  = threadIdx.x & 63;
    const int r0 = threadIdx.x >> 6;
    #pragma unroll
    for (int i=0;i<16;++i){
        int r = r0*16 + i;                     // k within block
        tile[r][c] = W[(size_t)(kb*64 + r)*64 + c];
    }
    __syncthreads();
    #pragma unroll
    for (int i=0;i<16;++i){
        int n = r0*16 + i;
        Wt[(size_t)(mb*64 + n)*1024 + kb*64 + c] = __float2bfloat16(tile[c][n]);
    }
}

// ---------- QKV projection: C[16384,192] = x[16384,1024] * Wt^T ----------
// grid 256 blocks x 256 thr; wave w owns rows [blk*64+16w, +16), all 192 cols (12 n-tiles).
// a-frags: x f32 from global (cvt to bf16), 2-step prefetch. b-frags: Wt bf16 direct from global (L2).
__global__ __launch_bounds__(256) void proj_kernel(
    const float* __restrict__ x, const __hip_bfloat16* __restrict__ Wt,
    __hip_bfloat16* __restrict__ Qo, __hip_bfloat16* __restrict__ Ko,
    __hip_bfloat16* __restrict__ Vo)
{
    const int tid = threadIdx.x;
    const int w = tid >> 6, l = tid & 63;
    const int l15 = l & 15, lg = l >> 4;

    const size_t row = (size_t)blockIdx.x*64 + w*16 + l15;
    const float* xr = x + row*E_ + lg*8;          // frag k-offset within 32-step = lg*8+j

    f32x4 acc[12];
    #pragma unroll
    for (int i=0;i<12;++i) acc[i] = (f32x4){0.f,0.f,0.f,0.f};

    const __hip_bfloat16* wp = Wt + (size_t)l15*1024 + lg*8;

    float4 aA0 = *(const float4*)(xr);      float4 aA1 = *(const float4*)(xr + 4);
    float4 aB0 = *(const float4*)(xr + 32); float4 aB1 = *(const float4*)(xr + 36);

    for (int ks=0; ks<32; ks+=2){
        {
            bf16x8 af = cvt8(aA0, aA1);
            if (ks+2 < 32){ aA0 = *(const float4*)(xr + (ks+2)*32); aA1 = *(const float4*)(xr + (ks+2)*32 + 4); }
            const __hip_bfloat16* wk = wp + ks*32;
            #pragma unroll
            for (int nt=0; nt<12; ++nt){
                bf16x8 bfr = *reinterpret_cast<const bf16x8*>(wk + (size_t)nt*16*1024);
                acc[nt] = __builtin_amdgcn_mfma_f32_16x16x32_bf16(af, bfr, acc[nt], 0,0,0);
            }
        }
        {
            bf16x8 af = cvt8(aB0, aB1);
            if (ks+3 < 32){ aB0 = *(const float4*)(xr + (ks+3)*32); aB1 = *(const float4*)(xr + (ks+3)*32 + 4); }
            const __hip_bfloat16* wk = wp + (ks+1)*32;
            #pragma unroll
            for (int nt=0; nt<12; ++nt){
                bf16x8 bfr = *reinterpret_cast<const bf16x8*>(wk + (size_t)nt*16*1024);
                acc[nt] = __builtin_amdgcn_mfma_f32_16x16x32_bf16(af, bfr, acc[nt], 0,0,0);
            }
        }
    }

    // C/D: lane holds row = lg*4 + r, col = nt*16 + l15
    const size_t orow = (size_t)blockIdx.x*64 + w*16 + lg*4;
    #pragma unroll
    for (int nt=0; nt<12; ++nt){
        __hip_bfloat16* base = (nt<4) ? Qo : (nt<8) ? Ko : Vo;
        const float sc = (nt<4) ? 0.125f : 1.0f;   // pre-scale Q by 1/sqrt(D)
        const int col = (nt&3)*16 + l15;
        #pragma unroll
        for (int r=0;r<4;++r)
            base[(orow + r)*64 + col] = __float2bfloat16(acc[nt][r]*sc);
    }
}

// ---------- flash attention: QBLK=64 (4 waves x 16 rows), KVB=64, D=64 ----------
__global__ __launch_bounds__(256) void fattn_kernel(
    const __hip_bfloat16* __restrict__ Qg, const __hip_bfloat16* __restrict__ Kg,
    const __hip_bfloat16* __restrict__ Vg, float* __restrict__ out)
{
    __shared__ __align__(16) unsigned short KT[64*64];     // [kv][d], swizzled
    __shared__ __align__(16) unsigned short VT[64*64];     // [d][kv], swizzled
    __shared__ __align__(16) unsigned short Pl[4][16*64];  // per-wave P [q][kv], swizzled

    const int tid = threadIdx.x;
    const int w = tid >> 6, l = tid & 63;
    const int l15 = l & 15, lg = l >> 4;
    const int b  = blockIdx.x >> 5;
    const int qt = blockIdx.x & 31;
    const int qbase = qt * 64;
    const size_t batchoff = (size_t)b * T_ * 64;

    // Q frags in registers (Q was pre-scaled by 0.125)
    const int qrow = qbase + w*16 + l15;
    bf16x8 qf[2];
    qf[0] = *reinterpret_cast<const bf16x8*>(Qg + batchoff + (size_t)qrow*64 + lg*8);
    qf[1] = *reinterpret_cast<const bf16x8*>(Qg + batchoff + (size_t)qrow*64 + 32 + lg*8);

    f32x4 o[4];
    #pragma unroll
    for (int i=0;i<4;++i) o[i] = (f32x4){0.f,0.f,0.f,0.f};
    float mrun[4] = {-1e30f,-1e30f,-1e30f,-1e30f};
    float lrun[4] = {0.f,0.f,0.f,0.f};

    char* pw = (char*)&Pl[w][0];
    const int nsteps = qt + 1;

    for (int st=0; st<nsteps; ++st){
        const int kv0 = st*64;
        // ---- stage K tile [kv][d] and V^T tile [d][kv], both XOR-swizzled ----
        const __hip_bfloat16* Kb = Kg + batchoff + (size_t)kv0*64;
        const __hip_bfloat16* Vb = Vg + batchoff + (size_t)kv0*64;
        #pragma unroll
        for (int i=0;i<2;++i){
            const int c = tid + i*256;
            const int row = c >> 3, c8 = c & 7;
            bf16x8 kd = *reinterpret_cast<const bf16x8*>(Kb + row*64 + c8*8);
            *reinterpret_cast<bf16x8*>((char*)KT + row*128 + ((c8*16) ^ ((row&7)<<4))) = kd;
            bf16x8 vd = *reinterpret_cast<const bf16x8*>(Vb + row*64 + c8*8);
            #pragma unroll
            for (int j=0;j<8;++j){
                const int d = c8*8 + j;
                *(unsigned short*)((char*)VT + d*128 + ((row*2) ^ ((d&7)<<4))) = (unsigned short)vd[j];
            }
        }
        __syncthreads();

        // ---- S = Q K^T : 8 MFMA/wave ----
        f32x4 s[4];
        #pragma unroll
        for (int nt=0; nt<4; ++nt) s[nt] = (f32x4){0.f,0.f,0.f,0.f};
        #pragma unroll
        for (int ks=0; ks<2; ++ks){
            #pragma unroll
            for (int nt=0; nt<4; ++nt){
                const int krow = nt*16 + l15;
                bf16x8 kf = *reinterpret_cast<const bf16x8*>(
                    (char*)KT + krow*128 + ((ks*64 + lg*16) ^ ((krow&7)<<4)));
                s[nt] = __builtin_amdgcn_mfma_f32_16x16x32_bf16(qf[ks], kf, s[nt], 0,0,0);
            }
        }

        // ---- causal mask (diagonal step only) ----
        if (st == qt){
            #pragma unroll
            for (int nt=0; nt<4; ++nt){
                const int kvc = kv0 + nt*16 + l15;
                #pragma unroll
                for (int r=0;r<4;++r){
                    const int qi = qbase + w*16 + lg*4 + r;
                    if (kvc > qi) s[nt][r] = -1e30f;
                }
            }
        }

        // ---- online softmax (rows = lg*4+r; 16-lane groups share a row) ----
        #pragma unroll
        for (int r=0;r<4;++r){
            float rm = fmaxf(fmaxf(s[0][r],s[1][r]), fmaxf(s[2][r],s[3][r]));
            rm = fmaxf(rm, __shfl_xor(rm, 1));
            rm = fmaxf(rm, __shfl_xor(rm, 2));
            rm = fmaxf(rm, __shfl_xor(rm, 4));
            rm = fmaxf(rm, __shfl_xor(rm, 8));
            const float mn = fmaxf(mrun[r], rm);
            const float sc = __expf(mrun[r] - mn);
            mrun[r] = mn;
            float rs = 0.f;
            #pragma unroll
            for (int nt=0;nt<4;++nt){
                const float p = __expf(s[nt][r] - mn);
                s[nt][r] = p; rs += p;
            }
            rs += __shfl_xor(rs, 1); rs += __shfl_xor(rs, 2);
            rs += __shfl_xor(rs, 4); rs += __shfl_xor(rs, 8);
            lrun[r] = lrun[r]*sc + rs;
            o[0][r]*=sc; o[1][r]*=sc; o[2][r]*=sc; o[3][r]*=sc;
        }

        // ---- P -> per-wave LDS (bf16, swizzled) ----
        #pragma unroll
        for (int nt=0;nt<4;++nt){
            #pragma unroll
            for (int r=0;r<4;++r){
                const int prow = lg*4 + r, pcol = nt*16 + l15;
                *(unsigned short*)(pw + prow*128 + ((pcol*2) ^ ((prow&7)<<4)))
                    = (unsigned short)f2bf(s[nt][r]);
            }
        }

        // ---- O += P V : 8 MFMA/wave ----
        #pragma unroll
        for (int ks=0; ks<2; ++ks){
            bf16x8 pf = *reinterpret_cast<const bf16x8*>(
                pw + l15*128 + ((ks*64 + lg*16) ^ ((l15&7)<<4)));
            #pragma unroll
            for (int dt=0; dt<4; ++dt){
                const int vrow = dt*16 + l15;
                bf16x8 vf = *reinterpret_cast<const bf16x8*>(
                    (char*)VT + vrow*128 + ((ks*64 + lg*16) ^ ((vrow&7)<<4)));
                o[dt] = __builtin_amdgcn_mfma_f32_16x16x32_bf16(pf, vf, o[dt], 0,0,0);
            }
        }
        __syncthreads();
    }

    // ---- epilogue ----
    float* ob = out + batchoff;
    #pragma unroll
    for (int dt=0; dt<4; ++dt){
        #pragma unroll
        for (int r=0;r<4;++r){
            const int qi = qbase + w*16 + lg*4 + r;
            ob[(size_t)qi*64 + dt*16 + l15] = o[dt][r] / lrun[r];
        }
    }
}

extern "C" void kernel_launch(void* const* d_in, const int* in_sizes, int n_in,
                              void* d_out, int out_size, void* d_ws, size_t ws_size,
                              hipStream_t stream) {
    const float* x  = (const float*)d_in[0];
    const float* Wq = (const float*)d_in[1];
    const float* Wk = (const float*)d_in[2];
    const float* Wv = (const float*)d_in[3];
    float* out = (float*)d_out;

    __hip_bfloat16* Wt = (__hip_bfloat16*)d_ws;                 // [192][1024]
    __hip_bfloat16* Qb = Wt + (size_t)192*1024;                 // [B*T,64] (pre-scaled)
    __hip_bfloat16* Kb = Qb + (size_t)B_*T_*64;                 // [B*T,64]
    __hip_bfloat16* Vb = Kb + (size_t)B_*T_*64;                 // [B*T,64]

    wconv_kernel<<<48, 256, 0, stream>>>(Wq, Wk, Wv, Wt);
    proj_kernel<<<(B_*T_)/64, 256, 0, stream>>>(x, Wt, Qb, Kb, Vb);
    fattn_kernel<<<(B_*T_)/64, 256, 0, stream>>>(Qb, Kb, Vb, out);
}

// Round 3
// 82.371 us; speedup vs baseline: 6.7484x; 1.9817x over previous
//
#include <hip/hip_runtime.h>
#include <hip/hip_bf16.h>
#include <cstdint>
#include <cstddef>

#define B_ 8
#define T_ 2048
#define E_ 1024
#define D_ 64

typedef __attribute__((ext_vector_type(8))) short bf16x8;
typedef __attribute__((ext_vector_type(4))) float f32x4;
typedef __attribute__((ext_vector_type(16))) float f32x16;

#define QSCALE 0.1803368801111204f  // 0.125 * log2(e): fold softmax scale + exp2 domain into Wq

__device__ __forceinline__ short f2bf(float f){
    __hip_bfloat16 h = __float2bfloat16(f);
    return *reinterpret_cast<short*>(&h);
}

__device__ __forceinline__ bf16x8 cvt8v(const f32x4 a, const f32x4 b){
    bf16x8 r;
    r[0]=f2bf(a[0]); r[1]=f2bf(a[1]); r[2]=f2bf(a[2]); r[3]=f2bf(a[3]);
    r[4]=f2bf(b[0]); r[5]=f2bf(b[1]); r[6]=f2bf(b[2]); r[7]=f2bf(b[3]);
    return r;
}

// ---------- W -> MFMA-fragment-linear layout ----------
// Wfrag element block (16B) index g = (cg*6 + ntg)*64 + lane; holds B[n=ntg*32+(l&31)][k=cg*16+(l>>5)*8+j]
// Wq pre-scaled by 0.125*log2e (softmax scale + exp2 domain).
__global__ __launch_bounds__(256) void wconv_kernel(
    const float* __restrict__ Wq, const float* __restrict__ Wk,
    const float* __restrict__ Wv, __hip_bfloat16* __restrict__ Wfrag)
{
    const int g = blockIdx.x*256 + threadIdx.x;   // [0, 24576)
    const int l = g & 63;
    const int ntg = (g >> 6) % 6;
    const int cg = g / 384;                        // k-chunk 0..63
    const int n = ntg*32 + (l & 31);
    const int m = n >> 6;                          // 0=Q,1=K,2=V
    const int ncol = n & 63;
    const float* W = (m==0) ? Wq : (m==1) ? Wk : Wv;
    const float sc = (m==0) ? QSCALE : 1.0f;
    const int k0 = cg*16 + (l>>5)*8;
    bf16x8 r;
    #pragma unroll
    for (int j=0;j<8;++j)
        r[j] = f2bf(W[(size_t)(k0+j)*64 + ncol] * sc);
    *reinterpret_cast<bf16x8*>(Wfrag + (size_t)g*8) = r;
}

// ---------- QKV projection: C[16384,192] = x * W, 32x32x16 MFMA ----------
// 256 blocks x 256 thr (4 waves = 2 m-halves x 2 n-halves). x staged in dbuf swizzled LDS.
__global__ __launch_bounds__(256) void proj_kernel(
    const float* __restrict__ x, const __hip_bfloat16* __restrict__ Wfrag,
    __hip_bfloat16* __restrict__ Qo, __hip_bfloat16* __restrict__ Ko,
    __hip_bfloat16* __restrict__ Vo)
{
    __shared__ float xs[2][64*64];   // 32 KB, granule-swizzled: granule ^= (row&15)
    const int tid = threadIdx.x;
    const int w = tid>>6, l = tid&63;
    const int mh = w>>1, nh = w&1;
    const int l31 = l&31, kg = l>>5;
    const int rowfull = mh*32 + l31;
    const float* xp = x + (size_t)blockIdx.x*64*E_;

    f32x16 acc[3];
    #pragma unroll
    for (int i=0;i<3;++i)
        #pragma unroll
        for (int j=0;j<16;++j) acc[i][j]=0.f;

    // prologue: stage k-step 0
    #pragma unroll
    for (int i=0;i<4;++i){
        const int lin = tid + i*256;
        const int row = lin>>4, colg = lin&15;
        f32x4 v = *reinterpret_cast<const f32x4*>(xp + (size_t)row*E_ + colg*4);
        *reinterpret_cast<f32x4*>((char*)&xs[0][0] + row*256 + ((colg ^ (row&15))<<4)) = v;
    }
    __syncthreads();

    const bf16x8* Wfp = reinterpret_cast<const bf16x8*>(Wfrag);

    for (int t=0; t<16; ++t){
        // B frags for this step (coalesced, L1/L2-hot)
        bf16x8 bt[12];
        #pragma unroll
        for (int c=0;c<4;++c)
            #pragma unroll
            for (int nt=0;nt<3;++nt)
                bt[c*3+nt] = Wfp[(size_t)(((t*4+c)*6 + (nh*3+nt))*64 + l)];

        // prefetch next x k-slice into regs (in flight during compute)
        f32x4 xa[4];
        if (t+1 < 16){
            #pragma unroll
            for (int i=0;i<4;++i){
                const int lin = tid + i*256;
                const int row = lin>>4, colg = lin&15;
                xa[i] = *reinterpret_cast<const f32x4*>(xp + (size_t)row*E_ + (t+1)*64 + colg*4);
            }
        }

        // compute 4 chunks (K=16 each)
        const char* xb = (const char*)&xs[t&1][0];
        #pragma unroll
        for (int c=0;c<4;++c){
            const int g0 = c*4 + kg*2;
            f32x4 a0 = *reinterpret_cast<const f32x4*>(xb + rowfull*256 + (((g0  ) ^ (rowfull&15))<<4));
            f32x4 a1 = *reinterpret_cast<const f32x4*>(xb + rowfull*256 + (((g0+1) ^ (rowfull&15))<<4));
            bf16x8 af = cvt8v(a0, a1);
            #pragma unroll
            for (int nt=0;nt<3;++nt)
                acc[nt] = __builtin_amdgcn_mfma_f32_32x32x16_bf16(af, bt[c*3+nt], acc[nt], 0,0,0);
        }

        // write next slice, one barrier per step
        if (t+1 < 16){
            #pragma unroll
            for (int i=0;i<4;++i){
                const int lin = tid + i*256;
                const int row = lin>>4, colg = lin&15;
                *reinterpret_cast<f32x4*>((char*)&xs[(t+1)&1][0] + row*256 + ((colg ^ (row&15))<<4)) = xa[i];
            }
            __syncthreads();
        }
    }

    // epilogue: C/D 32x32 layout col=l&31, row=(reg&3)+8*(reg>>2)+4*(l>>5)
    const size_t rowbase = (size_t)blockIdx.x*64 + mh*32;
    #pragma unroll
    for (int nt=0;nt<3;++nt){
        const int nbase = (nh*3+nt)*32;
        const int mat = nbase>>6;
        __hip_bfloat16* dst = (mat==0)?Qo:(mat==1)?Ko:Vo;
        const int col = (nbase&63) + l31;
        #pragma unroll
        for (int reg=0; reg<16; ++reg){
            const int mr = (reg&3) + 8*(reg>>2) + 4*kg;
            dst[(rowbase + mr)*64 + col] = __float2bfloat16(acc[nt][reg]);
        }
    }
}

// ---------- flash attention: QBLK=64, 8 waves = 2 KV-parity groups x 4 q-waves ----------
__global__ __launch_bounds__(512) void fattn_kernel(
    const __hip_bfloat16* __restrict__ Qg, const __hip_bfloat16* __restrict__ Kg,
    const __hip_bfloat16* __restrict__ Vg, float* __restrict__ out)
{
    __shared__ __align__(16) unsigned short KT[2][2][64*64];   // [round-parity][tile-slot][kv][d] swz
    __shared__ __align__(16) unsigned short VT[2][2][64*64];   // [..][..][d][kv] swz
    __shared__ __align__(16) unsigned short Pl[8][16*64];      // per-wave P

    const int tid = threadIdx.x;
    const int w = tid>>6, l = tid&63;
    const int qw = w&3, g = w>>2;
    const int l15 = l&15, lg = l>>4;

    // XCD swizzle: each XCD keeps one batch's K/V L2-resident
    const int lb = (blockIdx.x & 7)*32 + (blockIdx.x >> 3);
    const int b  = lb >> 5;
    const int qt = lb & 31;
    const int qbase = qt*64;
    const size_t batchoff = (size_t)b * T_ * 64;
    const int nsteps = qt + 1;
    const int R = (nsteps + 1) >> 1;

    const int qrow = qbase + qw*16 + l15;
    bf16x8 qf0 = *reinterpret_cast<const bf16x8*>(Qg + batchoff + (size_t)qrow*64 + lg*8);
    bf16x8 qf1 = *reinterpret_cast<const bf16x8*>(Qg + batchoff + (size_t)qrow*64 + 32 + lg*8);

    f32x4 o[4];
    #pragma unroll
    for (int i=0;i<4;++i) o[i] = (f32x4){0.f,0.f,0.f,0.f};
    float mrun[4] = {-1e30f,-1e30f,-1e30f,-1e30f};
    float lrun[4] = {0.f,0.f,0.f,0.f};

    const int srow = tid >> 3;   // 0..63
    const int sc8  = tid & 7;    // 0..7
    const __hip_bfloat16* Kb = Kg + batchoff;
    const __hip_bfloat16* Vb = Vg + batchoff;

    // prologue: stage tiles 0 (and 1) into parity 0
    {
        bf16x8 k0 = *reinterpret_cast<const bf16x8*>(Kb + (size_t)srow*64 + sc8*8);
        bf16x8 v0 = *reinterpret_cast<const bf16x8*>(Vb + (size_t)srow*64 + sc8*8);
        *reinterpret_cast<bf16x8*>((char*)&KT[0][0][0] + srow*128 + ((sc8*16) ^ ((srow&7)<<4))) = k0;
        #pragma unroll
        for (int j=0;j<8;++j){
            const int d = sc8*8+j;
            *reinterpret_cast<unsigned short*>((char*)&VT[0][0][0] + d*128 + ((srow*2) ^ ((d&7)<<4))) = (unsigned short)v0[j];
        }
        if (nsteps > 1){
            bf16x8 k1 = *reinterpret_cast<const bf16x8*>(Kb + (size_t)(64+srow)*64 + sc8*8);
            bf16x8 v1 = *reinterpret_cast<const bf16x8*>(Vb + (size_t)(64+srow)*64 + sc8*8);
            *reinterpret_cast<bf16x8*>((char*)&KT[0][1][0] + srow*128 + ((sc8*16) ^ ((srow&7)<<4))) = k1;
            #pragma unroll
            for (int j=0;j<8;++j){
                const int d = sc8*8+j;
                *reinterpret_cast<unsigned short*>((char*)&VT[0][1][0] + d*128 + ((srow*2) ^ ((d&7)<<4))) = (unsigned short)v1[j];
            }
        }
    }
    __syncthreads();

    char* pw = (char*)&Pl[w][0];

    for (int r=0; r<R; ++r){
        const int rb = r&1;
        // async-issue next round's K/V loads (T14)
        bf16x8 kn0, vn0, kn1, vn1;
        const int tn0 = 2*r+2, tn1 = 2*r+3;
        const bool ok0 = tn0 < nsteps, ok1 = tn1 < nsteps;
        if (ok0){
            kn0 = *reinterpret_cast<const bf16x8*>(Kb + (size_t)(tn0*64+srow)*64 + sc8*8);
            vn0 = *reinterpret_cast<const bf16x8*>(Vb + (size_t)(tn0*64+srow)*64 + sc8*8);
        }
        if (ok1){
            kn1 = *reinterpret_cast<const bf16x8*>(Kb + (size_t)(tn1*64+srow)*64 + sc8*8);
            vn1 = *reinterpret_cast<const bf16x8*>(Vb + (size_t)(tn1*64+srow)*64 + sc8*8);
        }

        // compute this group's tile
        const int st = 2*r + g;
        if (st < nsteps){
            const char* Kbuf = (const char*)&KT[rb][g][0];
            const char* Vbuf = (const char*)&VT[rb][g][0];
            f32x4 s[4];
            #pragma unroll
            for (int nt=0;nt<4;++nt) s[nt] = (f32x4){0.f,0.f,0.f,0.f};
            #pragma unroll
            for (int ks=0;ks<2;++ks){
                const bf16x8 qf = ks ? qf1 : qf0;
                #pragma unroll
                for (int nt=0;nt<4;++nt){
                    const int krow = nt*16 + l15;
                    bf16x8 kf = *reinterpret_cast<const bf16x8*>(Kbuf + krow*128 + ((ks*64 + lg*16) ^ ((krow&7)<<4)));
                    s[nt] = __builtin_amdgcn_mfma_f32_16x16x32_bf16(qf, kf, s[nt], 0,0,0);
                }
            }
            if (st == qt){
                #pragma unroll
                for (int nt=0;nt<4;++nt){
                    const int kvc = st*64 + nt*16 + l15;
                    #pragma unroll
                    for (int rr=0;rr<4;++rr){
                        const int qi = qbase + qw*16 + lg*4 + rr;
                        if (kvc > qi) s[nt][rr] = -1e30f;
                    }
                }
            }
            #pragma unroll
            for (int rr=0;rr<4;++rr){
                float rm = fmaxf(fmaxf(s[0][rr],s[1][rr]), fmaxf(s[2][rr],s[3][rr]));
                rm = fmaxf(rm, __shfl_xor(rm,1));
                rm = fmaxf(rm, __shfl_xor(rm,2));
                rm = fmaxf(rm, __shfl_xor(rm,4));
                rm = fmaxf(rm, __shfl_xor(rm,8));
                const float mn = fmaxf(mrun[rr], rm);
                const float scl = exp2f(mrun[rr] - mn);
                mrun[rr] = mn;
                float rs = 0.f;
                #pragma unroll
                for (int nt=0;nt<4;++nt){
                    const float p = exp2f(s[nt][rr] - mn);
                    s[nt][rr] = p; rs += p;
                }
                rs += __shfl_xor(rs,1); rs += __shfl_xor(rs,2);
                rs += __shfl_xor(rs,4); rs += __shfl_xor(rs,8);
                lrun[rr] = lrun[rr]*scl + rs;
                o[0][rr]*=scl; o[1][rr]*=scl; o[2][rr]*=scl; o[3][rr]*=scl;
            }
            #pragma unroll
            for (int nt=0;nt<4;++nt)
                #pragma unroll
                for (int rr=0;rr<4;++rr){
                    const int prow = lg*4+rr, pcol = nt*16+l15;
                    *reinterpret_cast<unsigned short*>(pw + prow*128 + ((pcol*2) ^ ((prow&7)<<4))) = (unsigned short)f2bf(s[nt][rr]);
                }
            #pragma unroll
            for (int ks=0;ks<2;++ks){
                bf16x8 pf = *reinterpret_cast<const bf16x8*>(pw + l15*128 + ((ks*64 + lg*16) ^ ((l15&7)<<4)));
                #pragma unroll
                for (int dt=0;dt<4;++dt){
                    const int vrow = dt*16 + l15;
                    bf16x8 vf = *reinterpret_cast<const bf16x8*>(Vbuf + vrow*128 + ((ks*64 + lg*16) ^ ((vrow&7)<<4)));
                    o[dt] = __builtin_amdgcn_mfma_f32_16x16x32_bf16(pf, vf, o[dt], 0,0,0);
                }
            }
        }

        // write next round's tiles into other parity; one barrier per round
        if (ok0){
            *reinterpret_cast<bf16x8*>((char*)&KT[rb^1][0][0] + srow*128 + ((sc8*16) ^ ((srow&7)<<4))) = kn0;
            #pragma unroll
            for (int j=0;j<8;++j){
                const int d = sc8*8+j;
                *reinterpret_cast<unsigned short*>((char*)&VT[rb^1][0][0] + d*128 + ((srow*2) ^ ((d&7)<<4))) = (unsigned short)vn0[j];
            }
        }
        if (ok1){
            *reinterpret_cast<bf16x8*>((char*)&KT[rb^1][1][0] + srow*128 + ((sc8*16) ^ ((srow&7)<<4))) = kn1;
            #pragma unroll
            for (int j=0;j<8;++j){
                const int d = sc8*8+j;
                *reinterpret_cast<unsigned short*>((char*)&VT[rb^1][1][0] + d*128 + ((srow*2) ^ ((d&7)<<4))) = (unsigned short)vn1[j];
            }
        }
        __syncthreads();
    }

    // ---- merge group1 into group0, write out ----
    __syncthreads();
    float* Obuf = (float*)&KT[0][0][0];   // 16 KB of the 32 KB KT area
    float* Mbuf = (float*)&VT[0][0][0];
    float* Lbuf = Mbuf + 64;
    if (g == 1){
        #pragma unroll
        for (int dt=0;dt<4;++dt)
            #pragma unroll
            for (int rr=0;rr<4;++rr)
                Obuf[(qw*16 + lg*4 + rr)*64 + dt*16 + l15] = o[dt][rr];
        if (l15 == 0){
            #pragma unroll
            for (int rr=0;rr<4;++rr){
                Mbuf[qw*16 + lg*4 + rr] = mrun[rr];
                Lbuf[qw*16 + lg*4 + rr] = lrun[rr];
            }
        }
    }
    __syncthreads();
    if (g == 0){
        float* ob = out + batchoff;
        #pragma unroll
        for (int rr=0;rr<4;++rr){
            const int ridx = qw*16 + lg*4 + rr;
            const float m1 = Mbuf[ridx], l1 = Lbuf[ridx];
            const float m = fmaxf(mrun[rr], m1);
            const float a0 = exp2f(mrun[rr]-m), a1 = exp2f(m1-m);
            const float inv = 1.0f/(lrun[rr]*a0 + l1*a1);
            const int qi = qbase + ridx;
            #pragma unroll
            for (int dt=0;dt<4;++dt){
                const float v1 = Obuf[ridx*64 + dt*16 + l15];
                ob[(size_t)qi*64 + dt*16 + l15] = (o[dt][rr]*a0 + v1*a1)*inv;
            }
        }
    }
}

extern "C" void kernel_launch(void* const* d_in, const int* in_sizes, int n_in,
                              void* d_out, int out_size, void* d_ws, size_t ws_size,
                              hipStream_t stream) {
    const float* x  = (const float*)d_in[0];
    const float* Wq = (const float*)d_in[1];
    const float* Wk = (const float*)d_in[2];
    const float* Wv = (const float*)d_in[3];
    float* out = (float*)d_out;

    __hip_bfloat16* Wfrag = (__hip_bfloat16*)d_ws;              // 24576*8 elems = 384 KB
    __hip_bfloat16* Qb = Wfrag + (size_t)24576*8;               // [B*T,64] (Q pre-scaled)
    __hip_bfloat16* Kb = Qb + (size_t)B_*T_*64;
    __hip_bfloat16* Vb = Kb + (size_t)B_*T_*64;

    wconv_kernel<<<96, 256, 0, stream>>>(Wq, Wk, Wv, Wfrag);
    proj_kernel<<<(B_*T_)/64, 256, 0, stream>>>(x, Wfrag, Qb, Kb, Vb);
    fattn_kernel<<<(B_*T_)/64, 512, 0, stream>>>(Qb, Kb, Vb, out);
}

// Round 4
// 58.802 us; speedup vs baseline: 9.4533x; 1.4008x over previous
//
#include <hip/hip_runtime.h>
#include <hip/hip_bf16.h>
#include <cstdint>
#include <cstddef>

#define B_ 8
#define T_ 2048
#define E_ 1024
#define D_ 64

typedef __attribute__((ext_vector_type(8))) short bf16x8;
typedef __attribute__((ext_vector_type(4))) float f32x4;
typedef __attribute__((ext_vector_type(16))) float f32x16;
typedef __attribute__((ext_vector_type(4))) unsigned short u16x4;

#define QSCALE 0.1803368801111204f  // 0.125 * log2(e): softmax scale + exp2 domain folded into Wq

__device__ __forceinline__ short f2bf(float f){
    __hip_bfloat16 h = __float2bfloat16(f);
    return *reinterpret_cast<short*>(&h);
}

__device__ __forceinline__ bf16x8 cvt8v(const f32x4 a, const f32x4 b){
    bf16x8 r;
    r[0]=f2bf(a[0]); r[1]=f2bf(a[1]); r[2]=f2bf(a[2]); r[3]=f2bf(a[3]);
    r[4]=f2bf(b[0]); r[5]=f2bf(b[1]); r[6]=f2bf(b[2]); r[7]=f2bf(b[3]);
    return r;
}

// ---------- W -> MFMA-fragment-linear layout ----------
__global__ __launch_bounds__(256) void wconv_kernel(
    const float* __restrict__ Wq, const float* __restrict__ Wk,
    const float* __restrict__ Wv, __hip_bfloat16* __restrict__ Wfrag)
{
    const int g = blockIdx.x*256 + threadIdx.x;   // [0, 24576)
    const int l = g & 63;
    const int ntg = (g >> 6) % 6;
    const int cg = g / 384;                        // k-chunk 0..63
    const int n = ntg*32 + (l & 31);
    const int m = n >> 6;                          // 0=Q,1=K,2=V
    const int ncol = n & 63;
    const float* W = (m==0) ? Wq : (m==1) ? Wk : Wv;
    const float sc = (m==0) ? QSCALE : 1.0f;
    const int k0 = cg*16 + (l>>5)*8;
    bf16x8 r;
    #pragma unroll
    for (int j=0;j<8;++j)
        r[j] = f2bf(W[(size_t)(k0+j)*64 + ncol] * sc);
    *reinterpret_cast<bf16x8*>(Wfrag + (size_t)g*8) = r;
}

// ---------- QKV projection ----------
// Outputs: Qo [B*T,64] (scaled), Ko [B*T,64], VTg [B][64][T] (V transposed, d-major)
__global__ __launch_bounds__(256, 1) void proj_kernel(
    const float* __restrict__ x, const __hip_bfloat16* __restrict__ Wfrag,
    __hip_bfloat16* __restrict__ Qo, __hip_bfloat16* __restrict__ Ko,
    __hip_bfloat16* __restrict__ VTg)
{
    __shared__ float xs[2][64*64];   // 32 KB, granule-swizzled
    const int tid = threadIdx.x;
    const int w = tid>>6, l = tid&63;
    const int mh = w>>1, nh = w&1;
    const int l31 = l&31, kg = l>>5;
    const int rowfull = mh*32 + l31;
    const float* xp = x + (size_t)blockIdx.x*64*E_;

    f32x16 acc[3];
    #pragma unroll
    for (int i=0;i<3;++i)
        #pragma unroll
        for (int j=0;j<16;++j) acc[i][j]=0.f;

    const bf16x8* Wfp = reinterpret_cast<const bf16x8*>(Wfrag);

    // B-frag ping-pong buffers
    bf16x8 btA[12], btB[12];
    #pragma unroll
    for (int c=0;c<4;++c)
        #pragma unroll
        for (int nt=0;nt<3;++nt)
            btA[c*3+nt] = Wfp[(size_t)(((0*4+c)*6 + (nh*3+nt))*64 + l)];

    // prologue: stage k-slice 0
    #pragma unroll
    for (int i=0;i<4;++i){
        const int lin = tid + i*256;
        const int row = lin>>4, colg = lin&15;
        f32x4 v = *reinterpret_cast<const f32x4*>(xp + (size_t)row*E_ + colg*4);
        *reinterpret_cast<f32x4*>((char*)&xs[0][0] + row*256 + ((colg ^ (row&15))<<4)) = v;
    }
    __syncthreads();

#define PROJ_STEP(T, BT_CUR, BT_NXT)                                          \
    {                                                                          \
        const int t = (T);                                                     \
        if (t+1 < 16){                                                         \
            _Pragma("unroll")                                                  \
            for (int c=0;c<4;++c)                                              \
                _Pragma("unroll")                                              \
                for (int nt=0;nt<3;++nt)                                       \
                    BT_NXT[c*3+nt] = Wfp[(size_t)((((t+1)*4+c)*6 + (nh*3+nt))*64 + l)]; \
        }                                                                      \
        f32x4 xa[4];                                                           \
        if (t+1 < 16){                                                         \
            _Pragma("unroll")                                                  \
            for (int i=0;i<4;++i){                                             \
                const int lin = tid + i*256;                                   \
                const int row = lin>>4, colg = lin&15;                         \
                xa[i] = *reinterpret_cast<const f32x4*>(xp + (size_t)row*E_ + (t+1)*64 + colg*4); \
            }                                                                  \
        }                                                                      \
        const char* xb = (const char*)&xs[t&1][0];                             \
        _Pragma("unroll")                                                      \
        for (int c=0;c<4;++c){                                                 \
            const int g0 = c*4 + kg*2;                                         \
            f32x4 a0 = *reinterpret_cast<const f32x4*>(xb + rowfull*256 + (((g0  ) ^ (rowfull&15))<<4)); \
            f32x4 a1 = *reinterpret_cast<const f32x4*>(xb + rowfull*256 + (((g0+1) ^ (rowfull&15))<<4)); \
            bf16x8 af = cvt8v(a0, a1);                                         \
            _Pragma("unroll")                                                  \
            for (int nt=0;nt<3;++nt)                                           \
                acc[nt] = __builtin_amdgcn_mfma_f32_32x32x16_bf16(af, BT_CUR[c*3+nt], acc[nt], 0,0,0); \
        }                                                                      \
        if (t+1 < 16){                                                         \
            _Pragma("unroll")                                                  \
            for (int i=0;i<4;++i){                                             \
                const int lin = tid + i*256;                                   \
                const int row = lin>>4, colg = lin&15;                         \
                *reinterpret_cast<f32x4*>((char*)&xs[(t+1)&1][0] + row*256 + ((colg ^ (row&15))<<4)) = xa[i]; \
            }                                                                  \
            __syncthreads();                                                   \
        }                                                                      \
    }

    for (int t2=0; t2<8; ++t2){
        PROJ_STEP(2*t2,   btA, btB)
        PROJ_STEP(2*t2+1, btB, btA)
    }
#undef PROJ_STEP

    // ---- epilogue: Q and K direct; V via LDS transpose -> VTg ----
    const size_t rowbase = (size_t)blockIdx.x*64 + mh*32;
    #pragma unroll
    for (int nt=0;nt<3;++nt){
        const int nbase = (nh*3+nt)*32;
        const int mat = nbase>>6;
        if (mat < 2){
            __hip_bfloat16* dst = (mat==0)?Qo:Ko;
            const int col = (nbase&63) + l31;
            #pragma unroll
            for (int reg=0; reg<16; ++reg){
                const int mr = (reg&3) + 8*(reg>>2) + 4*kg;
                dst[(rowbase + mr)*64 + col] = __float2bfloat16(acc[nt][reg]);
            }
        }
    }
    __syncthreads();   // xs free now
    float* vt = (float*)&xs[0][0];   // [64][65] padded
    if (nh == 1){
        #pragma unroll
        for (int nt=1;nt<3;++nt){
            const int dbase = (nt-1)*32;
            #pragma unroll
            for (int reg=0; reg<16; ++reg){
                const int mr = mh*32 + (reg&3) + 8*(reg>>2) + 4*kg;
                vt[mr*65 + dbase + l31] = acc[nt][reg];
            }
        }
    }
    __syncthreads();
    {
        const int bb = blockIdx.x >> 5;
        const int t0 = (blockIdx.x & 31)*64;
        const int d = tid >> 2, mseg = tid & 3;
        #pragma unroll
        for (int half=0; half<2; ++half){
            bf16x8 pk;
            #pragma unroll
            for (int j=0;j<8;++j)
                pk[j] = f2bf(vt[(mseg*16 + half*8 + j)*65 + d]);
            *reinterpret_cast<bf16x8*>(VTg + (size_t)bb*64*T_ + (size_t)d*T_ + t0 + mseg*16 + half*8) = pk;
        }
    }
}

// ---------- flash attention: swapped QK^T, per-lane q-row softmax ----------
__global__ __launch_bounds__(512) void fattn_kernel(
    const __hip_bfloat16* __restrict__ Qg, const __hip_bfloat16* __restrict__ Kg,
    const __hip_bfloat16* __restrict__ VTg, float* __restrict__ out)
{
    __shared__ __align__(16) unsigned short KT[2][2][64*64];   // [parity][slot][kv][d] swz
    __shared__ __align__(16) unsigned short VT[2][2][64*64];   // [parity][slot][d][kv] swz
    __shared__ __align__(16) unsigned short Pl[8][16*64];      // per-wave P[q][kv] swz

    const int tid = threadIdx.x;
    const int w = tid>>6, l = tid&63;
    const int qw = w&3, g = w>>2;
    const int l15 = l&15, lg = l>>4;

    const int lb = (blockIdx.x & 7)*32 + (blockIdx.x >> 3);   // XCD swizzle
    const int b  = lb >> 5;
    const int qt = lb & 31;
    const int qbase = qt*64;
    const size_t batchoff = (size_t)b * T_ * 64;
    const int nsteps = qt + 1;
    const int R = (nsteps + 1) >> 1;

    const int qrow = qbase + qw*16 + l15;
    bf16x8 qf0 = *reinterpret_cast<const bf16x8*>(Qg + batchoff + (size_t)qrow*64 + lg*8);
    bf16x8 qf1 = *reinterpret_cast<const bf16x8*>(Qg + batchoff + (size_t)qrow*64 + 32 + lg*8);

    // O^T accum: o[dt][r] = O[q=l15-row][d=dt*16+lg*4+r]
    f32x4 o[4];
    #pragma unroll
    for (int i=0;i<4;++i) o[i] = (f32x4){0.f,0.f,0.f,0.f};
    float mrun = -1e30f, lrun = 0.f;

    const int srow = tid>>3, sc8 = tid&7;
    const __hip_bfloat16* Kb = Kg + batchoff;
    const __hip_bfloat16* Vb = VTg + (size_t)b*64*T_;

    // prologue: stage tiles 0 (and 1) into parity 0
    {
        bf16x8 k0 = *reinterpret_cast<const bf16x8*>(Kb + (size_t)srow*64 + sc8*8);
        bf16x8 v0 = *reinterpret_cast<const bf16x8*>(Vb + (size_t)srow*T_ + sc8*8);
        *reinterpret_cast<bf16x8*>((char*)&KT[0][0][0] + srow*128 + ((sc8*16) ^ ((srow&7)<<4))) = k0;
        *reinterpret_cast<bf16x8*>((char*)&VT[0][0][0] + srow*128 + ((sc8*16) ^ ((srow&7)<<4))) = v0;
        if (nsteps > 1){
            bf16x8 k1 = *reinterpret_cast<const bf16x8*>(Kb + (size_t)(64+srow)*64 + sc8*8);
            bf16x8 v1 = *reinterpret_cast<const bf16x8*>(Vb + (size_t)srow*T_ + 64 + sc8*8);
            *reinterpret_cast<bf16x8*>((char*)&KT[0][1][0] + srow*128 + ((sc8*16) ^ ((srow&7)<<4))) = k1;
            *reinterpret_cast<bf16x8*>((char*)&VT[0][1][0] + srow*128 + ((sc8*16) ^ ((srow&7)<<4))) = v1;
        }
    }
    __syncthreads();

    char* pw = (char*)&Pl[w][0];

    for (int r=0; r<R; ++r){
        const int rb = r&1;
        // T14: issue next-round K/V loads into regs before compute
        bf16x8 kn0, vn0, kn1, vn1;
        const int tn0 = 2*r+2, tn1 = 2*r+3;
        const bool ok0 = tn0 < nsteps, ok1 = tn1 < nsteps;
        if (ok0){
            kn0 = *reinterpret_cast<const bf16x8*>(Kb + (size_t)(tn0*64+srow)*64 + sc8*8);
            vn0 = *reinterpret_cast<const bf16x8*>(Vb + (size_t)srow*T_ + tn0*64 + sc8*8);
        }
        if (ok1){
            kn1 = *reinterpret_cast<const bf16x8*>(Kb + (size_t)(tn1*64+srow)*64 + sc8*8);
            vn1 = *reinterpret_cast<const bf16x8*>(Vb + (size_t)srow*T_ + tn1*64 + sc8*8);
        }

        const int st = 2*r + g;
        if (st < nsteps){
            const char* Kbuf = (const char*)&KT[rb][g][0];
            const char* Vbuf = (const char*)&VT[rb][g][0];

            // ---- S^T = mfma(K, Q): lane holds S[q=l15][key=nt*16+lg*4+r] ----
            f32x4 s[4];
            #pragma unroll
            for (int nt=0;nt<4;++nt) s[nt] = (f32x4){0.f,0.f,0.f,0.f};
            __builtin_amdgcn_s_setprio(1);
            #pragma unroll
            for (int ks=0;ks<2;++ks){
                const bf16x8 qf = ks ? qf1 : qf0;
                #pragma unroll
                for (int nt=0;nt<4;++nt){
                    const int krow = nt*16 + l15;
                    bf16x8 kf = *reinterpret_cast<const bf16x8*>(Kbuf + krow*128 + ((ks*64 + lg*16) ^ ((krow&7)<<4)));
                    s[nt] = __builtin_amdgcn_mfma_f32_16x16x32_bf16(kf, qf, s[nt], 0,0,0);
                }
            }
            __builtin_amdgcn_s_setprio(0);

            // ---- causal mask (diagonal tile only) ----
            if (st == qt){
                #pragma unroll
                for (int nt=0;nt<4;++nt){
                    #pragma unroll
                    for (int rr=0;rr<4;++rr){
                        const int kv = st*64 + nt*16 + lg*4 + rr;
                        if (kv > qrow) s[nt][rr] = -1e30f;
                    }
                }
            }

            // ---- per-lane softmax (q-row = l15); 2 shfls total per reduce ----
            float pm;
            {
                float m0 = fmaxf(fmaxf(s[0][0],s[0][1]), fmaxf(s[0][2],s[0][3]));
                float m1 = fmaxf(fmaxf(s[1][0],s[1][1]), fmaxf(s[1][2],s[1][3]));
                float m2 = fmaxf(fmaxf(s[2][0],s[2][1]), fmaxf(s[2][2],s[2][3]));
                float m3 = fmaxf(fmaxf(s[3][0],s[3][1]), fmaxf(s[3][2],s[3][3]));
                pm = fmaxf(fmaxf(m0,m1), fmaxf(m2,m3));
            }
            pm = fmaxf(pm, __shfl_xor(pm, 16));
            pm = fmaxf(pm, __shfl_xor(pm, 32));
            if (pm > mrun + 8.0f){     // defer-max (T13)
                const float scl = exp2f(mrun - pm);
                mrun = pm;
                lrun *= scl;
                #pragma unroll
                for (int dt=0;dt<4;++dt)
                    #pragma unroll
                    for (int j=0;j<4;++j) o[dt][j] *= scl;
            }
            float rs = 0.f;
            #pragma unroll
            for (int nt=0;nt<4;++nt)
                #pragma unroll
                for (int rr=0;rr<4;++rr){
                    const float p = exp2f(s[nt][rr] - mrun);
                    s[nt][rr] = p; rs += p;
                }
            rs += __shfl_xor(rs, 16);
            rs += __shfl_xor(rs, 32);
            lrun += rs;

            // ---- P -> per-wave LDS (packed 8B writes) ----
            #pragma unroll
            for (int nt=0;nt<4;++nt){
                u16x4 pk;
                #pragma unroll
                for (int rr=0;rr<4;++rr) pk[rr] = (unsigned short)f2bf(s[nt][rr]);
                *reinterpret_cast<u16x4*>(pw + l15*128 + ((nt*32 + lg*8) ^ ((l15&7)<<4))) = pk;
            }

            // ---- O^T += mfma(V^T, P^T) ----
            __builtin_amdgcn_s_setprio(1);
            #pragma unroll
            for (int ks=0;ks<2;++ks){
                bf16x8 pf = *reinterpret_cast<const bf16x8*>(pw + l15*128 + ((ks*64 + lg*16) ^ ((l15&7)<<4)));
                #pragma unroll
                for (int dt=0;dt<4;++dt){
                    const int vrow = dt*16 + l15;
                    bf16x8 vf = *reinterpret_cast<const bf16x8*>(Vbuf + vrow*128 + ((ks*64 + lg*16) ^ ((vrow&7)<<4)));
                    o[dt] = __builtin_amdgcn_mfma_f32_16x16x32_bf16(vf, pf, o[dt], 0,0,0);
                }
            }
            __builtin_amdgcn_s_setprio(0);
        }

        // write next round's tiles into other parity
        if (ok0){
            *reinterpret_cast<bf16x8*>((char*)&KT[rb^1][0][0] + srow*128 + ((sc8*16) ^ ((srow&7)<<4))) = kn0;
            *reinterpret_cast<bf16x8*>((char*)&VT[rb^1][0][0] + srow*128 + ((sc8*16) ^ ((srow&7)<<4))) = vn0;
        }
        if (ok1){
            *reinterpret_cast<bf16x8*>((char*)&KT[rb^1][1][0] + srow*128 + ((sc8*16) ^ ((srow&7)<<4))) = kn1;
            *reinterpret_cast<bf16x8*>((char*)&VT[rb^1][1][0] + srow*128 + ((sc8*16) ^ ((srow&7)<<4))) = vn1;
        }
        __syncthreads();
    }

    // ---- merge group1 into group0, write out ----
    float* Obuf = (float*)&KT[0][0][0];   // 16 KB
    float* Mbuf = (float*)&VT[0][0][0];
    float* Lbuf = Mbuf + 64;
    const int ql = qw*16 + l15;
    if (g == 1){
        #pragma unroll
        for (int dt=0;dt<4;++dt)
            *reinterpret_cast<f32x4*>(&Obuf[ql*64 + dt*16 + lg*4]) = o[dt];
        if (lg == 0){ Mbuf[ql] = mrun; Lbuf[ql] = lrun; }
    }
    __syncthreads();
    if (g == 0){
        const float m1 = Mbuf[ql], l1 = Lbuf[ql];
        const float m = fmaxf(mrun, m1);
        const float a0 = exp2f(mrun - m), a1 = exp2f(m1 - m);
        const float inv = 1.0f/(lrun*a0 + l1*a1);
        #pragma unroll
        for (int dt=0;dt<4;++dt){
            f32x4 v1 = *reinterpret_cast<f32x4*>(&Obuf[ql*64 + dt*16 + lg*4]);
            f32x4 res;
            #pragma unroll
            for (int j=0;j<4;++j) res[j] = (o[dt][j]*a0 + v1[j]*a1)*inv;
            *reinterpret_cast<f32x4*>(out + batchoff + (size_t)qrow*64 + dt*16 + lg*4) = res;
        }
    }
}

extern "C" void kernel_launch(void* const* d_in, const int* in_sizes, int n_in,
                              void* d_out, int out_size, void* d_ws, size_t ws_size,
                              hipStream_t stream) {
    const float* x  = (const float*)d_in[0];
    const float* Wq = (const float*)d_in[1];
    const float* Wk = (const float*)d_in[2];
    const float* Wv = (const float*)d_in[3];
    float* out = (float*)d_out;

    __hip_bfloat16* Wfrag = (__hip_bfloat16*)d_ws;              // 384 KB
    __hip_bfloat16* Qb  = Wfrag + (size_t)24576*8;              // [B*T,64] (pre-scaled)
    __hip_bfloat16* Kb  = Qb + (size_t)B_*T_*64;                // [B*T,64]
    __hip_bfloat16* VTb = Kb + (size_t)B_*T_*64;                // [B][64][T] transposed

    wconv_kernel<<<96, 256, 0, stream>>>(Wq, Wk, Wv, Wfrag);
    proj_kernel<<<(B_*T_)/64, 256, 0, stream>>>(x, Wfrag, Qb, Kb, VTb);
    fattn_kernel<<<(B_*T_)/64, 512, 0, stream>>>(Qb, Kb, VTb, out);
}